// Round 7
// baseline (1327.775 us; speedup 1.0000x reference)
//
#include <hip/hip_runtime.h>

#define HH 256
#define WW 256
#define NPIX (HH*WW)
#define LL 16
#define NL (NPIX*LL)
#define PP 136
#define PP2 (PP*2)

typedef _Float16 half_t;
typedef __attribute__((ext_vector_type(8))) _Float16 half8;

// constants (double-evaluated, cast to float -- matches JAX weak-typed scalars)
static constexpr float SIGMAP_F = (float)((1.0/256.0)/(3.0+16.0)); // res/(3+l)
static constexpr float TAUU_F   = (float)((1.0/256.0)/6.0);        // res/6
static constexpr float TAU_F    = (float)(1.0/36.0);               // 1/(2+136/4)

__device__ __forceinline__ float clampf(float x, float lo, float hi){
    return fminf(fmaxf(x, lo), hi);
}

// ---------------- init: u/ubar = f broadcast; px/pt = 0; nrj = 0 -------------
__global__ __launch_bounds__(256) void k_init(const float* __restrict__ f,
    float* __restrict__ u, float* __restrict__ ubar,
    float* __restrict__ px, float* __restrict__ pt, float* __restrict__ nrj)
{
    int tid = blockIdx.x*256 + threadIdx.x;
    if (tid == 0) *nrj = 0.0f;
    if (tid >= NL) return;
    int n = tid >> 4;
    float fv = f[n];
    u[tid] = fv; ubar[tid] = fv;
    px[tid] = 0.0f; px[NL + tid] = 0.0f;
    pt[tid] = 0.0f;
}

// ---------------- prox: dual p update (per pixel,label) ----------------------
__global__ __launch_bounds__(256) void k_prox(const float* __restrict__ f,
    const float* __restrict__ ubar,
    float* __restrict__ px, float* __restrict__ pt,
    const half_t* __restrict__ musum)   // [d][n][z] fp16, full sum
{
    int tid = blockIdx.x*256 + threadIdx.x;
    if (tid >= NL) return;
    int z = tid & (LL-1);
    int n = tid >> 4;
    int i = n >> 8;
    int j = n & (WW-1);

    float ub = ubar[tid];
    float g0 = (i < HH-1) ? (ubar[tid + WW*LL] - ub) * 256.0f : 0.0f;
    float g1 = (j < WW-1) ? (ubar[tid + LL]    - ub) * 256.0f : 0.0f;
    float gt = (z < LL-1) ? (ubar[tid + 1]     - ub) * 16.0f  : 0.0f;

    float ms0 = (float)musum[tid];
    float ms1 = (float)musum[NL + tid];

    float ux0 = px[tid]      + SIGMAP_F * (g0 + ms0);
    float ux1 = px[NL + tid] + SIGMAP_F * (g1 + ms1);
    float ut  = pt[tid]      + SIGMAP_F * gt;

    float klf = (float)(z + 1) * 0.0625f - f[n];
    float pen = 0.5f * klf * klf;            // lmbda = 0.5

    float n2 = ux0*ux0 + ux1*ux1;
    float B  = 0.25f * n2 - pen;
    bool mask = ut < B;

    float px0 = ux0, px1 = ux1, ptn = ut;
    if (mask) {
        float y    = ut + pen;
        float norm = sqrtf(n2);
        float a    = 0.5f * norm;
        float b    = (2.0f/3.0f) * (1.0f - 0.5f*y);
        float v;
        if (b < 0.0f) {
            float sb  = sqrtf(-b);
            float sb3 = sb*sb*sb;
            float dd  = (a - sb3)*(a + sb3);
            if (dd < 0.0f) {
                float ratio = clampf(a / sb3, -1.0f, 1.0f);
                v = 2.0f * sb * cosf(acosf(ratio) * (1.0f/3.0f));
            } else {
                float c = cbrtf(a + sqrtf(dd));
                v = (c == 0.0f) ? 0.0f : (c - b/c);
            }
        } else {
            float dd = a*a + b*b*b;          // >= 0
            float c  = cbrtf(a + sqrtf(dd));
            v = (c == 0.0f) ? 0.0f : (c - b/c);
        }
        if (norm == 0.0f) { px0 = 0.0f; px1 = 0.0f; }
        else              { float s = 2.0f*v/norm; px0 = s*ux0; px1 = s*ux1; }
        ptn = 0.25f*(px0*px0 + px1*px1) - pen;
    }
    px[tid] = px0; px[NL + tid] = px1; pt[tid] = ptn;
}

// ---------------- fused s/mu update + primal u update ------------------------
// sx ELIMINATED: sx_{k-1} = (mu_{k-1} - mu_{k-2})/tau + t_prev (t_prev from
// the fp16 pxprev snapshot). mubar_k = 2*mu_{k-1} - mu_{k-2}. Two mu buffers
// ping-pong; only mu_k is written (into the mu_{k-2} slot).
// Geometry: 512-thread blocks = 8 waves; wave = row-set h (sets {H,15-H},
// 17 combos each, static). lane = pix*2 + d; shfl_xor(1) couples d=0/1.
// Partial musum accumulated via LDS atomicAdd into a 4 KB XOR-swizzled
// accumulator: idx = pix*32 + ((d*16+z)^pix) -> per-wave banks all distinct.
// mu storage (chunk-vectorized, per set H, per (n,d)): 17 elems = 8/8/1:
//   setbase = H*17*2*NPIX; chunk c at +c*16*NPIX + n*16 + d*8; tail at
//   +32*NPIX + n*2 + d.
__device__ __forceinline__ int pidx(int pix, int d, int z) {
    return (pix << 5) + (((d << 4) | z) ^ pix);
}

template<int H>
__device__ __forceinline__ void do_set(int d, int n, int pix,
    const float* __restrict__ p, const float* __restrict__ pp,
    const half_t* __restrict__ muC,   // mu_{k-1} (read)
    half_t* __restrict__ muO,         // mu_{k-2} (read) -> mu_k (write)
    float* __restrict__ part)
{
    constexpr size_t setbase = (size_t)H * 17 * 2 * NPIX;
    const size_t vb   = setbase + (size_t)n*16 + (size_t)d*8;    // chunk0
    const size_t vb1  = vb + (size_t)16*NPIX;                    // chunk1
    const size_t tail = setbase + (size_t)32*NPIX + (size_t)n*2 + (size_t)d;

    half8 mCv0 = *reinterpret_cast<const half8*>(&muC[vb]);
    half8 mCv1 = *reinterpret_cast<const half8*>(&muC[vb1]);
    half8 mOv0 = *reinterpret_cast<const half8*>(&muO[vb]);
    half8 mOv1 = *reinterpret_cast<const half8*>(&muO[vb1]);
    float mCT = (float)muC[tail];
    float mOT = (float)muO[tail];

    half8 muo0, muo1;
    half_t muoT = (half_t)0.0f;

    float C[LL];
    #pragma unroll
    for (int q = 0; q < LL; ++q) C[q] = 0.0f;   // only [H..15] ever written

    float tsum = 0.0f, tprev = 0.0f, rsA = 0.0f, rsB = 0.0f;
    #pragma unroll
    for (int q = 0; q < 17; ++q) {
        const int b = (q <= 15-H) ? H + q : q - 1;   // static under unroll
        float mC, mO;
        if (q < 8)       { mC=(float)mCv0[q];   mO=(float)mOv0[q]; }
        else if (q < 16) { mC=(float)mCv1[q-8]; mO=(float)mOv1[q-8]; }
        else             { mC=mCT;              mO=mOT; }

        if (q == 0 || q == 16-H) { tsum = 0.0f; tprev = 0.0f; }  // row start
        tsum  += p[b];
        tprev += pp[b];

        // sx_{k-1} = (mu_{k-1}-mu_{k-2})/tau + t_prev ; mx = sx - mubar
        float sxp = (mC - mO) * 36.0f + tprev;
        float mx  = sxp - (2.0f*mC - mO);
        float mo  = __shfl_xor(mx, 1);
        float snorm = sqrtf(mx*mx + mo*mo);
        if (snorm > 25.6f) mx *= 0.1f / snorm;       // nu*H ; nu/snorm
        float mn = mC + TAU_F*(mx - tsum);

        if (q < 8)       muo0[q]   = (half_t)mn;
        else if (q < 16) muo1[q-8] = (half_t)mn;
        else             muoT      = (half_t)mn;

        if (q <= 15-H) rsA += mn; else rsB += mn;
        C[b] += mn;
    }

    *reinterpret_cast<half8*>(&muO[vb])  = muo0;
    *reinterpret_cast<half8*>(&muO[vb1]) = muo1;
    muO[tail] = muoT;

    // partial musum recurrence (subset-valid) + LDS atomic accumulate:
    // ms[z] = ms[z-1] + RS[z] - C[z-1], RS nonzero only at z=H, z=15-H
    float m = 0.0f;
    #pragma unroll
    for (int z = 0; z < LL; ++z) {
        if (z == H)    m += rsA;
        if (z == 15-H) m += rsB;
        if (z >= 1)    m -= C[z-1];
        atomicAdd(&part[pidx(pix, d, z)], m);
    }
}

__global__ __launch_bounds__(512) void k_smu_u(const float* __restrict__ px,
    const float* __restrict__ pt,
    const half_t* __restrict__ muC,     // mu_{k-1}
    half_t* __restrict__ muO,           // mu_{k-2} -> mu_k
    half_t* __restrict__ pxprev,        // fp16 snapshot of previous px
    half_t* __restrict__ musum,         // [d][n][z] fp16 output
    float* __restrict__ u, float* __restrict__ ubar,
    float* __restrict__ nrj, int compute_nrj)
{
    __shared__ float part[1024];   // 4 KB swizzled accumulator [pix][d^z]
    __shared__ float wsum[8];

    int tid  = threadIdx.x;
    int wv   = tid >> 6;          // wave id = row-set h (0..7)
    int lane = tid & 63;
    int pix  = lane >> 1;
    int d    = lane & 1;
    int n    = blockIdx.x*32 + pix;

    part[tid]       = 0.0f;
    part[tid + 512] = 0.0f;

    // -------- load p (current px, fp32) and pp (prev px, fp16) --------
    float p[LL], pp[LL];
    {
        const float4* pxd = reinterpret_cast<const float4*>(px + (size_t)d*NL + (size_t)n*LL);
        #pragma unroll
        for (int q = 0; q < 4; ++q) {
            float4 a = pxd[q];
            p[4*q+0]=a.x; p[4*q+1]=a.y; p[4*q+2]=a.z; p[4*q+3]=a.w;
        }
        const half8* ppv = reinterpret_cast<const half8*>(pxprev + (size_t)d*NL + (size_t)n*LL);
        half8 v0 = ppv[0], v1 = ppv[1];
        #pragma unroll
        for (int q = 0; q < 8; ++q) { pp[q] = (float)v0[q]; pp[q+8] = (float)v1[q]; }
    }
    __syncthreads();   // part zeroed; pp reads done before wave 1 overwrites

    // -------- phase A: s & mu (per wave = one row set) --------
    if      (wv == 0) do_set<0>(d,n,pix,p,pp,muC,muO,part);
    else if (wv == 1) do_set<1>(d,n,pix,p,pp,muC,muO,part);
    else if (wv == 2) do_set<2>(d,n,pix,p,pp,muC,muO,part);
    else if (wv == 3) do_set<3>(d,n,pix,p,pp,muC,muO,part);
    else if (wv == 4) do_set<4>(d,n,pix,p,pp,muC,muO,part);
    else if (wv == 5) do_set<5>(d,n,pix,p,pp,muC,muO,part);
    else if (wv == 6) do_set<6>(d,n,pix,p,pp,muC,muO,part);
    else              do_set<7>(d,n,pix,p,pp,muC,muO,part);

    // wave 1 snapshots current px -> pxprev (fp16) for the next iteration
    if (wv == 1) {
        half8 o0, o1;
        #pragma unroll
        for (int q = 0; q < 8; ++q) { o0[q] = (half_t)p[q]; o1[q] = (half_t)p[q+8]; }
        half8* dst = reinterpret_cast<half8*>(pxprev + (size_t)d*NL + (size_t)n*LL);
        dst[0] = o0; dst[1] = o1;
    }
    __syncthreads();   // all atomics done

    // -------- write fp16 musum (coalesced: z fastest, then pix) --------
    #pragma unroll
    for (int r = 0; r < 2; ++r) {
        int pix2 = tid >> 4;
        int z2   = tid & 15;
        float s = part[pidx(pix2, r, z2)];
        musum[(size_t)r*NL + ((size_t)blockIdx.x*32 + pix2)*LL + z2] = (half_t)s;
    }

    // -------- phase B: primal u update (1 z per thread) --------
    // independent of phase A (depends only on prox outputs)
    {
        int t  = blockIdx.x*512 + tid;   // [0, NL)
        int z  = t & (LL-1);
        int n2 = t >> 4;
        int i2 = n2 >> 8;
        int j2 = n2 & (WW-1);

        float p0c = px[t];
        float p1c = px[NL + t];
        float d0 = ((i2 < HH-1) ? p0c : 0.0f) - ((i2 > 0) ? px[t - WW*LL] : 0.0f);
        float d1 = ((j2 < WW-1) ? p1c : 0.0f) - ((j2 > 0) ? px[NL + t - LL] : 0.0f);
        float ptc = pt[t];
        float dt = ((z < LL-1) ? ptc : 0.0f) - ((z > 0) ? pt[t - 1] : 0.0f);

        float uo = u[t];
        float Dv = uo + TAUU_F * ((d0 + d1) * 256.0f + dt * 16.0f);
        float un = clampf(Dv, 0.0f, 1.0f);
        if (z == 0)     un = 1.0f;
        if (z == LL-1)  un = 0.0f;
        u[t]    = un;
        ubar[t] = 2.0f*un - uo;

        if (compute_nrj) {
            float v = fabsf(un - uo);
            #pragma unroll
            for (int off = 32; off > 0; off >>= 1) v += __shfl_down(v, off);
            if ((tid & 63) == 0) wsum[wv] = v;
            __syncthreads();
            if (tid == 0) {
                float s = 0.0f;
                #pragma unroll
                for (int q = 0; q < 8; ++q) s += wsum[q];
                atomicAdd(nrj, s);
            }
        }
    }
}

// ---------------- tail scalars ----------------------------------------------
__global__ void k_final(const float* __restrict__ nrj, float* __restrict__ out_tail)
{
    if (threadIdx.x == 0) {
        float e = *nrj;
        out_tail[0] = e;
        out_tail[1] = e * (1.0f/1048576.0f);   // nrj / (H*W*1*l)
        out_tail[2] = 0.0f;
    }
}

extern "C" void kernel_launch(void* const* d_in, const int* in_sizes, int n_in,
                              void* d_out, int out_size, void* d_ws, size_t ws_size,
                              hipStream_t stream)
{
    const float* f = (const float*)d_in[0];
    float* out = (float*)d_out;

    char* w = (char*)d_ws;
    size_t off = 0;
    auto allocf = [&](size_t nfloats) {
        float* p = (float*)(w + off);
        off += nfloats * sizeof(float);
        return p;
    };
    auto alloch = [&](size_t nhalf) {
        half_t* p = (half_t*)(w + off);
        off += nhalf * sizeof(half_t);
        return p;
    };
    // fp16 block (memset together): muA, muB, musum, pxprev
    half_t* muA    = alloch((size_t)NPIX * PP2);   // 35.7 MB
    half_t* muB    = alloch((size_t)NPIX * PP2);   // 35.7 MB
    half_t* musum  = alloch(2*(size_t)NL);         // 4.2 MB
    half_t* pxprev = alloch(2*(size_t)NL);         // 4.2 MB
    size_t half_bytes = off;
    float*  px    = allocf(2*(size_t)NL);          // 8.4 MB
    float*  pt    = allocf((size_t)NL);            // 4.2 MB
    float*  u     = allocf((size_t)NL);            // 4.2 MB
    float*  ubar  = allocf((size_t)NL);            // 4.2 MB
    float*  nrj   = allocf(64);
    (void)ws_size; (void)in_sizes; (void)n_in; (void)out_size;

    hipMemsetAsync(muA, 0, half_bytes, stream);
    k_init<<<NL/256, 256, 0, stream>>>(f, u, ubar, px, pt, nrj);

    half_t* mC = muA;   // mu_{k-1} (zeros initially)
    half_t* mO = muB;   // mu_{k-2} (zeros initially), becomes mu_k
    for (int it = 0; it < 10; ++it) {
        k_prox<<<NL/256, 256, 0, stream>>>(f, ubar, px, pt, musum);
        k_smu_u<<<NPIX/32, 512, 0, stream>>>(px, pt, mC, mO, pxprev, musum,
                                             u, ubar, nrj, it == 0 ? 1 : 0);
        { half_t* tmp = mC; mC = mO; mO = tmp; }  // mO-buffer now holds mu_k
    }

    hipMemcpyAsync(out, u, (size_t)NL*sizeof(float), hipMemcpyDeviceToDevice, stream);
    k_final<<<1, 64, 0, stream>>>(nrj, out + NL);
}

// Round 8
// 613.684 us; speedup vs baseline: 2.1636x; 2.1636x over previous
//
#include <hip/hip_runtime.h>

#define HH 256
#define WW 256
#define NPIX (HH*WW)
#define LL 16
#define NL (NPIX*LL)
#define PP 136
#define PP2 (PP*2)

typedef _Float16 half_t;
typedef __attribute__((ext_vector_type(8))) _Float16 half8;

// constants (double-evaluated, cast to float -- matches JAX weak-typed scalars)
static constexpr float SIGMAP_F = (float)((1.0/256.0)/(3.0+16.0)); // res/(3+l)
static constexpr float TAUU_F   = (float)((1.0/256.0)/6.0);        // res/6
static constexpr float TAU_F    = (float)(1.0/36.0);               // 1/(2+136/4)

__device__ __forceinline__ float clampf(float x, float lo, float hi){
    return fminf(fmaxf(x, lo), hi);
}

// ---------------- init: u/ubar = f broadcast; px/pt = 0; nrj = 0 -------------
__global__ __launch_bounds__(256) void k_init(const float* __restrict__ f,
    float* __restrict__ u, float* __restrict__ ubar,
    float* __restrict__ px, float* __restrict__ pt, float* __restrict__ nrj)
{
    int tid = blockIdx.x*256 + threadIdx.x;
    if (tid == 0) *nrj = 0.0f;
    if (tid >= NL) return;
    int n = tid >> 4;
    float fv = f[n];
    u[tid] = fv; ubar[tid] = fv;
    px[tid] = 0.0f; px[NL + tid] = 0.0f;
    pt[tid] = 0.0f;
}

// ---------------- prox: dual p update (per pixel,label) ----------------------
__global__ __launch_bounds__(256) void k_prox(const float* __restrict__ f,
    const float* __restrict__ ubar,
    float* __restrict__ px, float* __restrict__ pt,
    const half_t* __restrict__ musum)   // [d][n][z] fp16, full sum
{
    int tid = blockIdx.x*256 + threadIdx.x;
    if (tid >= NL) return;
    int z = tid & (LL-1);
    int n = tid >> 4;
    int i = n >> 8;
    int j = n & (WW-1);

    float ub = ubar[tid];
    float g0 = (i < HH-1) ? (ubar[tid + WW*LL] - ub) * 256.0f : 0.0f;
    float g1 = (j < WW-1) ? (ubar[tid + LL]    - ub) * 256.0f : 0.0f;
    float gt = (z < LL-1) ? (ubar[tid + 1]     - ub) * 16.0f  : 0.0f;

    float ms0 = (float)musum[tid];
    float ms1 = (float)musum[NL + tid];

    float ux0 = px[tid]      + SIGMAP_F * (g0 + ms0);
    float ux1 = px[NL + tid] + SIGMAP_F * (g1 + ms1);
    float ut  = pt[tid]      + SIGMAP_F * gt;

    float klf = (float)(z + 1) * 0.0625f - f[n];
    float pen = 0.5f * klf * klf;            // lmbda = 0.5

    float n2 = ux0*ux0 + ux1*ux1;
    float B  = 0.25f * n2 - pen;
    bool mask = ut < B;

    float px0 = ux0, px1 = ux1, ptn = ut;
    if (mask) {
        float y    = ut + pen;
        float norm = sqrtf(n2);
        float a    = 0.5f * norm;
        float b    = (2.0f/3.0f) * (1.0f - 0.5f*y);
        float v;
        if (b < 0.0f) {
            float sb  = sqrtf(-b);
            float sb3 = sb*sb*sb;
            float dd  = (a - sb3)*(a + sb3);
            if (dd < 0.0f) {
                float ratio = clampf(a / sb3, -1.0f, 1.0f);
                v = 2.0f * sb * cosf(acosf(ratio) * (1.0f/3.0f));
            } else {
                float c = cbrtf(a + sqrtf(dd));
                v = (c == 0.0f) ? 0.0f : (c - b/c);
            }
        } else {
            float dd = a*a + b*b*b;          // >= 0
            float c  = cbrtf(a + sqrtf(dd));
            v = (c == 0.0f) ? 0.0f : (c - b/c);
        }
        if (norm == 0.0f) { px0 = 0.0f; px1 = 0.0f; }
        else              { float s = 2.0f*v/norm; px0 = s*ux0; px1 = s*ux1; }
        ptn = 0.25f*(px0*px0 + px1*px1) - pen;
    }
    px[tid] = px0; px[NL + tid] = px1; pt[tid] = ptn;
}

// ---------------- fused s/mu update + primal u update ------------------------
// sx ELIMINATED: sx_{k-1} = (mu_{k-1} - mu_{k-2})/tau + t_prev (t_prev from
// the fp16 pxprev snapshot). mubar_k = 2*mu_{k-1} - mu_{k-2}. Two mu buffers
// ping-pong; only mu_k is written (into the mu_{k-2} slot).
// Geometry: 512-thread blocks = 8 waves; wave = row-set h (sets {H,15-H},
// 17 combos each, static). lane = pix*2 + d; shfl_xor(1) couples d=0/1.
// Partial musum: per-wave STAGED partials in part[h][z][lane] (NOT atomics --
// round-7 post-mortem: 8-way same-address LDS atomicAdd serialized the DS
// pipe, 2.2x regression). All 8*16*64 = 8192 slots written unconditionally
// (no zero-init). Writes: per z a wave stores 64 consecutive floats -> 2
// lanes/bank = free. Reduce reads: per h a wave reads 64 consecutive -> free.
// mu storage (chunk-vectorized, per set H, per (n,d)): 17 elems = 8/8/1:
//   setbase = H*17*2*NPIX; chunk c at +c*16*NPIX + n*16 + d*8; tail at
//   +32*NPIX + n*2 + d.
template<int H>
__device__ __forceinline__ void do_set(int d, int n, int lane,
    const float* __restrict__ p, const float* __restrict__ pp,
    const half_t* __restrict__ muC,   // mu_{k-1} (read)
    half_t* __restrict__ muO,         // mu_{k-2} (read) -> mu_k (write)
    float* __restrict__ part)
{
    constexpr size_t setbase = (size_t)H * 17 * 2 * NPIX;
    const size_t vb   = setbase + (size_t)n*16 + (size_t)d*8;    // chunk0
    const size_t vb1  = vb + (size_t)16*NPIX;                    // chunk1
    const size_t tail = setbase + (size_t)32*NPIX + (size_t)n*2 + (size_t)d;

    half8 mCv0 = *reinterpret_cast<const half8*>(&muC[vb]);
    half8 mCv1 = *reinterpret_cast<const half8*>(&muC[vb1]);
    half8 mOv0 = *reinterpret_cast<const half8*>(&muO[vb]);
    half8 mOv1 = *reinterpret_cast<const half8*>(&muO[vb1]);
    float mCT = (float)muC[tail];
    float mOT = (float)muO[tail];

    half8 muo0, muo1;
    half_t muoT = (half_t)0.0f;

    float C[LL];
    #pragma unroll
    for (int q = 0; q < LL; ++q) C[q] = 0.0f;   // only [H..15] ever written

    float tsum = 0.0f, tprev = 0.0f, rsA = 0.0f, rsB = 0.0f;
    #pragma unroll
    for (int q = 0; q < 17; ++q) {
        const int b = (q <= 15-H) ? H + q : q - 1;   // static under unroll
        float mC, mO;
        if (q < 8)       { mC=(float)mCv0[q];   mO=(float)mOv0[q]; }
        else if (q < 16) { mC=(float)mCv1[q-8]; mO=(float)mOv1[q-8]; }
        else             { mC=mCT;              mO=mOT; }

        if (q == 0 || q == 16-H) { tsum = 0.0f; tprev = 0.0f; }  // row start
        tsum  += p[b];
        tprev += pp[b];

        // sx_{k-1} = (mu_{k-1}-mu_{k-2})/tau + t_prev ; mx = sx - mubar
        float sxp = (mC - mO) * 36.0f + tprev;
        float mx  = sxp - (2.0f*mC - mO);
        float mo  = __shfl_xor(mx, 1);
        float snorm = sqrtf(mx*mx + mo*mo);
        if (snorm > 25.6f) mx *= 0.1f / snorm;       // nu*H ; nu/snorm
        float mn = mC + TAU_F*(mx - tsum);

        if (q < 8)       muo0[q]   = (half_t)mn;
        else if (q < 16) muo1[q-8] = (half_t)mn;
        else             muoT      = (half_t)mn;

        if (q <= 15-H) rsA += mn; else rsB += mn;
        C[b] += mn;
    }

    *reinterpret_cast<half8*>(&muO[vb])  = muo0;
    *reinterpret_cast<half8*>(&muO[vb1]) = muo1;
    muO[tail] = muoT;

    // partial musum recurrence (subset-valid), staged to part[H][z][lane]:
    // ms[z] = ms[z-1] + RS[z] - C[z-1], RS nonzero only at z=H, z=15-H
    float m = 0.0f;
    #pragma unroll
    for (int z = 0; z < LL; ++z) {
        if (z == H)    m += rsA;
        if (z == 15-H) m += rsB;
        if (z >= 1)    m -= C[z-1];
        part[H*1024 + z*64 + lane] = m;
    }
}

__global__ __launch_bounds__(512) void k_smu_u(const float* __restrict__ px,
    const float* __restrict__ pt,
    const half_t* __restrict__ muC,     // mu_{k-1}
    half_t* __restrict__ muO,           // mu_{k-2} -> mu_k
    half_t* __restrict__ pxprev,        // fp16 snapshot of previous px
    half_t* __restrict__ musum,         // [d][n][z] fp16 output
    float* __restrict__ u, float* __restrict__ ubar,
    float* __restrict__ nrj, int compute_nrj)
{
    __shared__ float part[8192];   // 32 KB: [h][z][lane], all slots written
    __shared__ float wsum[8];

    int tid  = threadIdx.x;
    int wv   = tid >> 6;          // wave id = row-set h (0..7)
    int lane = tid & 63;
    int pix  = lane >> 1;
    int d    = lane & 1;
    int n    = blockIdx.x*32 + pix;

    // -------- load p (current px, fp32) and pp (prev px, fp16) --------
    float p[LL], pp[LL];
    {
        const float4* pxd = reinterpret_cast<const float4*>(px + (size_t)d*NL + (size_t)n*LL);
        #pragma unroll
        for (int q = 0; q < 4; ++q) {
            float4 a = pxd[q];
            p[4*q+0]=a.x; p[4*q+1]=a.y; p[4*q+2]=a.z; p[4*q+3]=a.w;
        }
        const half8* ppv = reinterpret_cast<const half8*>(pxprev + (size_t)d*NL + (size_t)n*LL);
        half8 v0 = ppv[0], v1 = ppv[1];
        #pragma unroll
        for (int q = 0; q < 8; ++q) { pp[q] = (float)v0[q]; pp[q+8] = (float)v1[q]; }
    }
    __syncthreads();   // all pp reads done before wave 1 overwrites pxprev

    // -------- phase A: s & mu (per wave = one row set) --------
    if      (wv == 0) do_set<0>(d,n,lane,p,pp,muC,muO,part);
    else if (wv == 1) do_set<1>(d,n,lane,p,pp,muC,muO,part);
    else if (wv == 2) do_set<2>(d,n,lane,p,pp,muC,muO,part);
    else if (wv == 3) do_set<3>(d,n,lane,p,pp,muC,muO,part);
    else if (wv == 4) do_set<4>(d,n,lane,p,pp,muC,muO,part);
    else if (wv == 5) do_set<5>(d,n,lane,p,pp,muC,muO,part);
    else if (wv == 6) do_set<6>(d,n,lane,p,pp,muC,muO,part);
    else              do_set<7>(d,n,lane,p,pp,muC,muO,part);

    // wave 1 snapshots current px -> pxprev (fp16) for the next iteration
    if (wv == 1) {
        half8 o0, o1;
        #pragma unroll
        for (int q = 0; q < 8; ++q) { o0[q] = (half_t)p[q]; o1[q] = (half_t)p[q+8]; }
        half8* dst = reinterpret_cast<half8*>(pxprev + (size_t)d*NL + (size_t)n*LL);
        dst[0] = o0; dst[1] = o1;
    }
    __syncthreads();   // all staged partials visible

    // -------- reduce partials over h, store fp16 musum --------
    // round r: z2 = (tid>>6)+8r, inner = tid&63 -> consecutive LDS addrs
    #pragma unroll
    for (int r = 0; r < 2; ++r) {
        int z2    = (tid >> 6) + r*8;
        int inner = tid & 63;
        float s = 0.0f;
        #pragma unroll
        for (int hh = 0; hh < 8; ++hh) s += part[hh*1024 + z2*64 + inner];
        int d2 = inner & 1, pix2 = inner >> 1;
        musum[(size_t)d2*NL + ((size_t)blockIdx.x*32 + pix2)*LL + z2] = (half_t)s;
    }

    // -------- phase B: primal u update (1 z per thread) --------
    // independent of phase A (depends only on prox outputs)
    {
        int t  = blockIdx.x*512 + tid;   // [0, NL)
        int z  = t & (LL-1);
        int n2 = t >> 4;
        int i2 = n2 >> 8;
        int j2 = n2 & (WW-1);

        float p0c = px[t];
        float p1c = px[NL + t];
        float d0 = ((i2 < HH-1) ? p0c : 0.0f) - ((i2 > 0) ? px[t - WW*LL] : 0.0f);
        float d1 = ((j2 < WW-1) ? p1c : 0.0f) - ((j2 > 0) ? px[NL + t - LL] : 0.0f);
        float ptc = pt[t];
        float dt = ((z < LL-1) ? ptc : 0.0f) - ((z > 0) ? pt[t - 1] : 0.0f);

        float uo = u[t];
        float Dv = uo + TAUU_F * ((d0 + d1) * 256.0f + dt * 16.0f);
        float un = clampf(Dv, 0.0f, 1.0f);
        if (z == 0)     un = 1.0f;
        if (z == LL-1)  un = 0.0f;
        u[t]    = un;
        ubar[t] = 2.0f*un - uo;

        if (compute_nrj) {
            float v = fabsf(un - uo);
            #pragma unroll
            for (int off = 32; off > 0; off >>= 1) v += __shfl_down(v, off);
            if ((tid & 63) == 0) wsum[wv] = v;
            __syncthreads();
            if (tid == 0) {
                float s = 0.0f;
                #pragma unroll
                for (int q = 0; q < 8; ++q) s += wsum[q];
                atomicAdd(nrj, s);
            }
        }
    }
}

// ---------------- tail scalars ----------------------------------------------
__global__ void k_final(const float* __restrict__ nrj, float* __restrict__ out_tail)
{
    if (threadIdx.x == 0) {
        float e = *nrj;
        out_tail[0] = e;
        out_tail[1] = e * (1.0f/1048576.0f);   // nrj / (H*W*1*l)
        out_tail[2] = 0.0f;
    }
}

extern "C" void kernel_launch(void* const* d_in, const int* in_sizes, int n_in,
                              void* d_out, int out_size, void* d_ws, size_t ws_size,
                              hipStream_t stream)
{
    const float* f = (const float*)d_in[0];
    float* out = (float*)d_out;

    char* w = (char*)d_ws;
    size_t off = 0;
    auto allocf = [&](size_t nfloats) {
        float* p = (float*)(w + off);
        off += nfloats * sizeof(float);
        return p;
    };
    auto alloch = [&](size_t nhalf) {
        half_t* p = (half_t*)(w + off);
        off += nhalf * sizeof(half_t);
        return p;
    };
    // fp16 block (memset together): muA, muB, musum, pxprev
    half_t* muA    = alloch((size_t)NPIX * PP2);   // 35.7 MB
    half_t* muB    = alloch((size_t)NPIX * PP2);   // 35.7 MB
    half_t* musum  = alloch(2*(size_t)NL);         // 4.2 MB
    half_t* pxprev = alloch(2*(size_t)NL);         // 4.2 MB
    size_t half_bytes = off;
    float*  px    = allocf(2*(size_t)NL);          // 8.4 MB
    float*  pt    = allocf((size_t)NL);            // 4.2 MB
    float*  u     = allocf((size_t)NL);            // 4.2 MB
    float*  ubar  = allocf((size_t)NL);            // 4.2 MB
    float*  nrj   = allocf(64);
    (void)ws_size; (void)in_sizes; (void)n_in; (void)out_size;

    hipMemsetAsync(muA, 0, half_bytes, stream);
    k_init<<<NL/256, 256, 0, stream>>>(f, u, ubar, px, pt, nrj);

    half_t* mC = muA;   // mu_{k-1} (zeros initially)
    half_t* mO = muB;   // mu_{k-2} (zeros initially), becomes mu_k
    for (int it = 0; it < 10; ++it) {
        k_prox<<<NL/256, 256, 0, stream>>>(f, ubar, px, pt, musum);
        k_smu_u<<<NPIX/32, 512, 0, stream>>>(px, pt, mC, mO, pxprev, musum,
                                             u, ubar, nrj, it == 0 ? 1 : 0);
        { half_t* tmp = mC; mC = mO; mO = tmp; }  // mO-buffer now holds mu_k
    }

    hipMemcpyAsync(out, u, (size_t)NL*sizeof(float), hipMemcpyDeviceToDevice, stream);
    k_final<<<1, 64, 0, stream>>>(nrj, out + NL);
}

// Round 9
// 453.594 us; speedup vs baseline: 2.9272x; 1.3529x over previous
//
#include <hip/hip_runtime.h>

#define HH 256
#define WW 256
#define NPIX (HH*WW)
#define LL 16
#define NL (NPIX*LL)
#define PP 136
#define PP2 (PP*2)

typedef _Float16 half_t;
typedef __attribute__((ext_vector_type(8))) _Float16 half8;

// constants (double-evaluated, cast to float -- matches JAX weak-typed scalars)
static constexpr float SIGMAP_F = (float)((1.0/256.0)/(3.0+16.0)); // res/(3+l)
static constexpr float TAUU_F   = (float)((1.0/256.0)/6.0);        // res/6
static constexpr float TAU_F    = (float)(1.0/36.0);               // 1/(2+136/4)

__device__ __forceinline__ float clampf(float x, float lo, float hi){
    return fminf(fmaxf(x, lo), hi);
}

// ---------------- init: u (fp32) and ubar (fp16) = f; nrj = 0 ----------------
// (px0/px1/pt/mu/musum zeroed by the preceding hipMemsetAsync)
__global__ __launch_bounds__(256) void k_init(const float* __restrict__ f,
    float* __restrict__ u, half_t* __restrict__ ubar, float* __restrict__ nrj)
{
    int tid = blockIdx.x*256 + threadIdx.x;
    if (tid == 0) *nrj = 0.0f;
    if (tid >= NL) return;
    int n = tid >> 4;
    float fv = f[n];
    u[tid]    = fv;
    ubar[tid] = (half_t)fv;
}

// ---------------- prox: dual p update (per pixel,label) ----------------------
// All small fields fp16: ubar, pxOld (read) / pxCur (write), pt (in place),
// musum. Math in fp32.
__global__ __launch_bounds__(256) void k_prox(const float* __restrict__ f,
    const half_t* __restrict__ ubar,
    const half_t* __restrict__ pxOld,   // px(it-1)
    half_t* __restrict__ pxCur,         // px(it) out
    half_t* __restrict__ pt,            // in-place
    const half_t* __restrict__ musum)   // [d][n][z]
{
    int tid = blockIdx.x*256 + threadIdx.x;
    if (tid >= NL) return;
    int z = tid & (LL-1);
    int n = tid >> 4;
    int i = n >> 8;
    int j = n & (WW-1);

    float ub = (float)ubar[tid];
    float g0 = (i < HH-1) ? ((float)ubar[tid + WW*LL] - ub) * 256.0f : 0.0f;
    float g1 = (j < WW-1) ? ((float)ubar[tid + LL]    - ub) * 256.0f : 0.0f;
    float gt = (z < LL-1) ? ((float)ubar[tid + 1]     - ub) * 16.0f  : 0.0f;

    float ms0 = (float)musum[tid];
    float ms1 = (float)musum[NL + tid];

    float ux0 = (float)pxOld[tid]      + SIGMAP_F * (g0 + ms0);
    float ux1 = (float)pxOld[NL + tid] + SIGMAP_F * (g1 + ms1);
    float ut  = (float)pt[tid]         + SIGMAP_F * gt;

    float klf = (float)(z + 1) * 0.0625f - f[n];
    float pen = 0.5f * klf * klf;            // lmbda = 0.5

    float n2 = ux0*ux0 + ux1*ux1;
    float B  = 0.25f * n2 - pen;
    bool mask = ut < B;

    float px0 = ux0, px1 = ux1, ptn = ut;
    if (mask) {
        float y    = ut + pen;
        float norm = sqrtf(n2);
        float a    = 0.5f * norm;
        float b    = (2.0f/3.0f) * (1.0f - 0.5f*y);
        float v;
        if (b < 0.0f) {
            float sb  = sqrtf(-b);
            float sb3 = sb*sb*sb;
            float dd  = (a - sb3)*(a + sb3);
            if (dd < 0.0f) {
                float ratio = clampf(a / sb3, -1.0f, 1.0f);
                v = 2.0f * sb * cosf(acosf(ratio) * (1.0f/3.0f));
            } else {
                float c = cbrtf(a + sqrtf(dd));
                v = (c == 0.0f) ? 0.0f : (c - b/c);
            }
        } else {
            float dd = a*a + b*b*b;          // >= 0
            float c  = cbrtf(a + sqrtf(dd));
            v = (c == 0.0f) ? 0.0f : (c - b/c);
        }
        if (norm == 0.0f) { px0 = 0.0f; px1 = 0.0f; }
        else              { float s = 2.0f*v/norm; px0 = s*ux0; px1 = s*ux1; }
        ptn = 0.25f*(px0*px0 + px1*px1) - pen;
    }
    pxCur[tid]      = (half_t)px0;
    pxCur[NL + tid] = (half_t)px1;
    pt[tid]         = (half_t)ptn;
}

// ---------------- fused s/mu update + primal u update ------------------------
// sx ELIMINATED: sx_{k-1} = (mu_{k-1} - mu_{k-2})/tau + t_prev; t_prev from
// pxOld (the px ping-pong replaces the old pxprev snapshot -> no intra-kernel
// WAR hazard, no pre-phase barrier). mubar = 2*mu_{k-1} - mu_{k-2}; mu buffers
// ping-pong, only mu_k written.
// Geometry: 512-thread blocks = 8 waves; wave = row-set h (sets {H,15-H},
// 17 combos each, static indices). lane = pix*2 + d; shfl_xor(1) couples d.
// p/pp stay PACKED half8 in registers (unpacked per-use, static idx) to keep
// VGPR <= 64 -> 8 waves/SIMD.
// Partial musum staged in part[h][z][lane] fp32 (all 8192 slots written; no
// zero-init; conflict-free writes & reads).
// mu storage (chunk-vectorized, per set H, per (n,d)): 17 elems = 8/8/1.
template<int H>
__device__ __forceinline__ void do_set(int d, int n, int lane,
    half8 ph0, half8 ph1, half8 pp0, half8 pp1,
    const half_t* __restrict__ muC,   // mu_{k-1} (read)
    half_t* __restrict__ muO,         // mu_{k-2} (read) -> mu_k (write)
    float* __restrict__ part)
{
    constexpr size_t setbase = (size_t)H * 17 * 2 * NPIX;
    const size_t vb   = setbase + (size_t)n*16 + (size_t)d*8;    // chunk0
    const size_t vb1  = vb + (size_t)16*NPIX;                    // chunk1
    const size_t tail = setbase + (size_t)32*NPIX + (size_t)n*2 + (size_t)d;

    half8 mCv0 = *reinterpret_cast<const half8*>(&muC[vb]);
    half8 mCv1 = *reinterpret_cast<const half8*>(&muC[vb1]);
    half8 mOv0 = *reinterpret_cast<const half8*>(&muO[vb]);
    half8 mOv1 = *reinterpret_cast<const half8*>(&muO[vb1]);
    float mCT = (float)muC[tail];
    float mOT = (float)muO[tail];

    half8 muo0, muo1;
    half_t muoT = (half_t)0.0f;

    float C[LL];
    #pragma unroll
    for (int q = 0; q < LL; ++q) C[q] = 0.0f;   // only [H..15] ever written

    float tsum = 0.0f, tprev = 0.0f, rsA = 0.0f, rsB = 0.0f;
    #pragma unroll
    for (int q = 0; q < 17; ++q) {
        const int b = (q <= 15-H) ? H + q : q - 1;   // static under unroll
        float mC, mO;
        if (q < 8)       { mC=(float)mCv0[q];   mO=(float)mOv0[q]; }
        else if (q < 16) { mC=(float)mCv1[q-8]; mO=(float)mOv1[q-8]; }
        else             { mC=mCT;              mO=mOT; }

        if (q == 0 || q == 16-H) { tsum = 0.0f; tprev = 0.0f; }  // row start
        tsum  += (b < 8) ? (float)ph0[b] : (float)ph1[b-8];
        tprev += (b < 8) ? (float)pp0[b] : (float)pp1[b-8];

        // sx_{k-1} = (mu_{k-1}-mu_{k-2})/tau + t_prev ; mx = sx - mubar
        float sxp = (mC - mO) * 36.0f + tprev;
        float mx  = sxp - (2.0f*mC - mO);
        float mo  = __shfl_xor(mx, 1);
        float snorm = sqrtf(mx*mx + mo*mo);
        if (snorm > 25.6f) mx *= 0.1f / snorm;       // nu*H ; nu/snorm
        float mn = mC + TAU_F*(mx - tsum);

        if (q < 8)       muo0[q]   = (half_t)mn;
        else if (q < 16) muo1[q-8] = (half_t)mn;
        else             muoT      = (half_t)mn;

        if (q <= 15-H) rsA += mn; else rsB += mn;
        C[b] += mn;
    }

    *reinterpret_cast<half8*>(&muO[vb])  = muo0;
    *reinterpret_cast<half8*>(&muO[vb1]) = muo1;
    muO[tail] = muoT;

    // partial musum recurrence (subset-valid), staged to part[H][z][lane]:
    // ms[z] = ms[z-1] + RS[z] - C[z-1], RS nonzero only at z=H, z=15-H
    float m = 0.0f;
    #pragma unroll
    for (int z = 0; z < LL; ++z) {
        if (z == H)    m += rsA;
        if (z == 15-H) m += rsB;
        if (z >= 1)    m -= C[z-1];
        part[H*1024 + z*64 + lane] = m;
    }
}

__global__ __launch_bounds__(512) void k_smu_u(
    const half_t* __restrict__ pxCur,   // px(it)   [d][n][z] fp16
    const half_t* __restrict__ pxOld,   // px(it-1) [d][n][z] fp16
    const half_t* __restrict__ pt,
    const half_t* __restrict__ muC,     // mu_{k-1}
    half_t* __restrict__ muO,           // mu_{k-2} -> mu_k
    half_t* __restrict__ musum,         // [d][n][z] fp16 output
    float* __restrict__ u, half_t* __restrict__ ubar,
    float* __restrict__ nrj, int compute_nrj)
{
    __shared__ float part[8192];   // 32 KB: [h][z][lane], all slots written
    __shared__ float wsum[8];

    int tid  = threadIdx.x;
    int wv   = tid >> 6;          // wave id = row-set h (0..7)
    int lane = tid & 63;
    int pix  = lane >> 1;
    int d    = lane & 1;
    int n    = blockIdx.x*32 + pix;

    // -------- load p (current px) and pp (prev px), packed half8 --------
    const half8* pv  = reinterpret_cast<const half8*>(pxCur + (size_t)d*NL + (size_t)n*LL);
    const half8* ppv = reinterpret_cast<const half8*>(pxOld + (size_t)d*NL + (size_t)n*LL);
    half8 ph0 = pv[0],  ph1 = pv[1];
    half8 pp0 = ppv[0], pp1 = ppv[1];

    // -------- phase A: s & mu (per wave = one row set) --------
    if      (wv == 0) do_set<0>(d,n,lane,ph0,ph1,pp0,pp1,muC,muO,part);
    else if (wv == 1) do_set<1>(d,n,lane,ph0,ph1,pp0,pp1,muC,muO,part);
    else if (wv == 2) do_set<2>(d,n,lane,ph0,ph1,pp0,pp1,muC,muO,part);
    else if (wv == 3) do_set<3>(d,n,lane,ph0,ph1,pp0,pp1,muC,muO,part);
    else if (wv == 4) do_set<4>(d,n,lane,ph0,ph1,pp0,pp1,muC,muO,part);
    else if (wv == 5) do_set<5>(d,n,lane,ph0,ph1,pp0,pp1,muC,muO,part);
    else if (wv == 6) do_set<6>(d,n,lane,ph0,ph1,pp0,pp1,muC,muO,part);
    else              do_set<7>(d,n,lane,ph0,ph1,pp0,pp1,muC,muO,part);

    __syncthreads();   // all staged partials visible

    // -------- reduce partials over h, store fp16 musum --------
    // round r: z2 = (tid>>6)+8r, inner = tid&63 -> consecutive LDS addrs
    #pragma unroll
    for (int r = 0; r < 2; ++r) {
        int z2    = (tid >> 6) + r*8;
        int inner = tid & 63;
        float s = 0.0f;
        #pragma unroll
        for (int hh = 0; hh < 8; ++hh) s += part[hh*1024 + z2*64 + inner];
        int d2 = inner & 1, pix2 = inner >> 1;
        musum[(size_t)d2*NL + ((size_t)blockIdx.x*32 + pix2)*LL + z2] = (half_t)s;
    }

    // -------- phase B: primal u update (1 z per thread) --------
    // independent of phase A (depends only on prox outputs)
    {
        int t  = blockIdx.x*512 + tid;   // [0, NL)
        int z  = t & (LL-1);
        int n2 = t >> 4;
        int i2 = n2 >> 8;
        int j2 = n2 & (WW-1);

        float p0c = (float)pxCur[t];
        float p1c = (float)pxCur[NL + t];
        float d0 = ((i2 < HH-1) ? p0c : 0.0f) - ((i2 > 0) ? (float)pxCur[t - WW*LL] : 0.0f);
        float d1 = ((j2 < WW-1) ? p1c : 0.0f) - ((j2 > 0) ? (float)pxCur[NL + t - LL] : 0.0f);
        float ptc = (float)pt[t];
        float dt = ((z < LL-1) ? ptc : 0.0f) - ((z > 0) ? (float)pt[t - 1] : 0.0f);

        float uo = u[t];
        float Dv = uo + TAUU_F * ((d0 + d1) * 256.0f + dt * 16.0f);
        float un = clampf(Dv, 0.0f, 1.0f);
        if (z == 0)     un = 1.0f;
        if (z == LL-1)  un = 0.0f;
        u[t]    = un;
        ubar[t] = (half_t)(2.0f*un - uo);

        if (compute_nrj) {
            float v = fabsf(un - uo);
            #pragma unroll
            for (int off = 32; off > 0; off >>= 1) v += __shfl_down(v, off);
            if ((tid & 63) == 0) wsum[wv] = v;
            __syncthreads();
            if (tid == 0) {
                float s = 0.0f;
                #pragma unroll
                for (int q = 0; q < 8; ++q) s += wsum[q];
                atomicAdd(nrj, s);
            }
        }
    }
}

// ---------------- tail scalars ----------------------------------------------
__global__ void k_final(const float* __restrict__ nrj, float* __restrict__ out_tail)
{
    if (threadIdx.x == 0) {
        float e = *nrj;
        out_tail[0] = e;
        out_tail[1] = e * (1.0f/1048576.0f);   // nrj / (H*W*1*l)
        out_tail[2] = 0.0f;
    }
}

extern "C" void kernel_launch(void* const* d_in, const int* in_sizes, int n_in,
                              void* d_out, int out_size, void* d_ws, size_t ws_size,
                              hipStream_t stream)
{
    const float* f = (const float*)d_in[0];
    float* out = (float*)d_out;

    char* w = (char*)d_ws;
    size_t off = 0;
    auto allocf = [&](size_t nfloats) {
        float* p = (float*)(w + off);
        off += nfloats * sizeof(float);
        return p;
    };
    auto alloch = [&](size_t nhalf) {
        half_t* p = (half_t*)(w + off);
        off += nhalf * sizeof(half_t);
        return p;
    };
    // fp16 block (single memset): muA, muB, musum, px ping-pong, pt, ubar
    half_t* muA    = alloch((size_t)NPIX * PP2);   // 35.7 MB
    half_t* muB    = alloch((size_t)NPIX * PP2);   // 35.7 MB
    half_t* musum  = alloch(2*(size_t)NL);         // 4.2 MB
    half_t* pxA    = alloch(2*(size_t)NL);         // 4.2 MB
    half_t* pxB    = alloch(2*(size_t)NL);         // 4.2 MB
    half_t* pt     = alloch((size_t)NL);           // 2.1 MB
    half_t* ubar   = alloch((size_t)NL);           // 2.1 MB
    size_t half_bytes = off;
    float*  u      = allocf((size_t)NL);           // 4.2 MB
    float*  nrj    = allocf(64);
    (void)ws_size; (void)in_sizes; (void)n_in; (void)out_size;

    hipMemsetAsync(muA, 0, half_bytes, stream);
    k_init<<<NL/256, 256, 0, stream>>>(f, u, ubar, nrj);

    half_t* pxC = pxA;  // px(it)
    half_t* pxO = pxB;  // px(it-1), zeros initially
    half_t* mC  = muA;  // mu_{k-1}, zeros initially
    half_t* mO  = muB;  // mu_{k-2}, zeros initially -> becomes mu_k
    for (int it = 0; it < 10; ++it) {
        k_prox<<<NL/256, 256, 0, stream>>>(f, ubar, pxO, pxC, pt, musum);
        k_smu_u<<<NPIX/32, 512, 0, stream>>>(pxC, pxO, pt, mC, mO, musum,
                                             u, ubar, nrj, it == 0 ? 1 : 0);
        { half_t* tmp = pxC; pxC = pxO; pxO = tmp; }
        { half_t* tmp = mC;  mC  = mO;  mO  = tmp; }  // mO-buffer holds mu_k
    }

    hipMemcpyAsync(out, u, (size_t)NL*sizeof(float), hipMemcpyDeviceToDevice, stream);
    k_final<<<1, 64, 0, stream>>>(nrj, out + NL);
}

// Round 10
// 423.668 us; speedup vs baseline: 3.1340x; 1.0706x over previous
//
#include <hip/hip_runtime.h>

#define HH 256
#define WW 256
#define NPIX (HH*WW)
#define LL 16
#define NL (NPIX*LL)
#define PP 136
#define PP2 (PP*2)

typedef _Float16 half_t;
typedef __attribute__((ext_vector_type(8))) _Float16 half8;

// constants (double-evaluated, cast to float -- matches JAX weak-typed scalars)
static constexpr float SIGMAP_F = (float)((1.0/256.0)/(3.0+16.0)); // res/(3+l)
static constexpr float TAUU_F   = (float)((1.0/256.0)/6.0);        // res/6
static constexpr float TAU_F    = (float)(1.0/36.0);               // 1/(2+136/4)

__device__ __forceinline__ float clampf(float x, float lo, float hi){
    return fminf(fmaxf(x, lo), hi);
}

// ---------------- prox: dual p update (per pixel,label) ----------------------
// MODE 0 (it=0): all state analytically zero -- reads ONLY f; ubar0 = f
// broadcast => gt = 0, musum = 0, px = 0, pt = 0. Thread 0 zeroes nrj.
// MODE 1 (steady): reads fp16 ubar/pxOld/pt/musum. Math in fp32.
template<int MODE>
__global__ __launch_bounds__(256) void k_prox(const float* __restrict__ f,
    const half_t* __restrict__ ubar,
    const half_t* __restrict__ pxOld,   // px(it-1)
    half_t* __restrict__ pxCur,         // px(it) out
    half_t* __restrict__ pt,            // in-place
    const half_t* __restrict__ musum,   // [d][n][z]
    float* __restrict__ nrj)
{
    int tid = blockIdx.x*256 + threadIdx.x;
    if (MODE == 0 && tid == 0) *nrj = 0.0f;
    if (tid >= NL) return;
    int z = tid & (LL-1);
    int n = tid >> 4;
    int i = n >> 8;
    int j = n & (WW-1);

    float ux0, ux1, ut;
    float fv = f[n];
    if (MODE == 0) {
        float g0 = (i < HH-1) ? (f[n + WW] - fv) * 256.0f : 0.0f;
        float g1 = (j < WW-1) ? (f[n + 1]  - fv) * 256.0f : 0.0f;
        ux0 = SIGMAP_F * g0;
        ux1 = SIGMAP_F * g1;
        ut  = 0.0f;
    } else {
        float ub = (float)ubar[tid];
        float g0 = (i < HH-1) ? ((float)ubar[tid + WW*LL] - ub) * 256.0f : 0.0f;
        float g1 = (j < WW-1) ? ((float)ubar[tid + LL]    - ub) * 256.0f : 0.0f;
        float gt = (z < LL-1) ? ((float)ubar[tid + 1]     - ub) * 16.0f  : 0.0f;
        float ms0 = (float)musum[tid];
        float ms1 = (float)musum[NL + tid];
        ux0 = (float)pxOld[tid]      + SIGMAP_F * (g0 + ms0);
        ux1 = (float)pxOld[NL + tid] + SIGMAP_F * (g1 + ms1);
        ut  = (float)pt[tid]         + SIGMAP_F * gt;
    }

    float klf = (float)(z + 1) * 0.0625f - fv;
    float pen = 0.5f * klf * klf;            // lmbda = 0.5

    float n2 = ux0*ux0 + ux1*ux1;
    float B  = 0.25f * n2 - pen;
    bool mask = ut < B;

    float px0 = ux0, px1 = ux1, ptn = ut;
    if (mask) {
        float y    = ut + pen;
        float norm = sqrtf(n2);
        float a    = 0.5f * norm;
        float b    = (2.0f/3.0f) * (1.0f - 0.5f*y);
        float v;
        if (b < 0.0f) {
            float sb  = sqrtf(-b);
            float sb3 = sb*sb*sb;
            float dd  = (a - sb3)*(a + sb3);
            if (dd < 0.0f) {
                float ratio = clampf(a / sb3, -1.0f, 1.0f);
                v = 2.0f * sb * cosf(acosf(ratio) * (1.0f/3.0f));
            } else {
                float c = cbrtf(a + sqrtf(dd));
                v = (c == 0.0f) ? 0.0f : (c - b/c);
            }
        } else {
            float dd = a*a + b*b*b;          // >= 0
            float c  = cbrtf(a + sqrtf(dd));
            v = (c == 0.0f) ? 0.0f : (c - b/c);
        }
        if (norm == 0.0f) { px0 = 0.0f; px1 = 0.0f; }
        else              { float s = 2.0f*v/norm; px0 = s*ux0; px1 = s*ux1; }
        ptn = 0.25f*(px0*px0 + px1*px1) - pen;
    }
    pxCur[tid]      = (half_t)px0;
    pxCur[NL + tid] = (half_t)px1;
    pt[tid]         = (half_t)ptn;
}

// ---------------- fused s/mu update + primal u update ------------------------
// sx ELIMINATED: sx_{k-1} = (mu_{k-1} - mu_{k-2})/tau + t_prev (t_prev from
// pxOld). mubar = 2*mu_{k-1} - mu_{k-2}; mu buffers ping-pong, only mu_k
// written. MODE 0 (it=0): mu,pxOld all zero -> mn = -tau*tsum, no mu/pxOld
// loads, phase-B uo = f[n]. MODE 1 (it=1): mu_{k-2} == 0 -> skip muO read
// (buffer is poisoned; fully overwritten). MODE 2: steady.
// Geometry: 512-thread blocks = 8 waves; wave = row-set h (sets {H,15-H},
// 17 combos each, static indices). lane = pix*2 + d; shfl_xor(1) couples d.
// Partial musum staged in part[h][z][lane] fp32 (conflict-free, all written).
template<int H, int MODE>
__device__ __forceinline__ void do_set(int d, int n, int lane,
    half8 ph0, half8 ph1, half8 pp0, half8 pp1,
    const half_t* __restrict__ muC,   // mu_{k-1} (read, MODE 2|1)
    half_t* __restrict__ muO,         // mu_{k-2} (read, MODE 2) -> mu_k (write)
    float* __restrict__ part)
{
    constexpr size_t setbase = (size_t)H * 17 * 2 * NPIX;
    const size_t vb   = setbase + (size_t)n*16 + (size_t)d*8;    // chunk0
    const size_t vb1  = vb + (size_t)16*NPIX;                    // chunk1
    const size_t tail = setbase + (size_t)32*NPIX + (size_t)n*2 + (size_t)d;

    half8 mCv0, mCv1, mOv0, mOv1;
    float mCT = 0.0f, mOT = 0.0f;
    if (MODE >= 1) {
        mCv0 = *reinterpret_cast<const half8*>(&muC[vb]);
        mCv1 = *reinterpret_cast<const half8*>(&muC[vb1]);
        mCT  = (float)muC[tail];
    }
    if (MODE == 2) {
        mOv0 = *reinterpret_cast<const half8*>(&muO[vb]);
        mOv1 = *reinterpret_cast<const half8*>(&muO[vb1]);
        mOT  = (float)muO[tail];
    }

    half8 muo0, muo1;
    half_t muoT = (half_t)0.0f;

    float C[LL];
    #pragma unroll
    for (int q = 0; q < LL; ++q) C[q] = 0.0f;   // only [H..15] ever written

    float tsum = 0.0f, tprev = 0.0f, rsA = 0.0f, rsB = 0.0f;
    #pragma unroll
    for (int q = 0; q < 17; ++q) {
        const int b = (q <= 15-H) ? H + q : q - 1;   // static under unroll
        if (q == 0 || q == 16-H) { tsum = 0.0f; tprev = 0.0f; }  // row start
        tsum  += (b < 8) ? (float)ph0[b] : (float)ph1[b-8];

        float mn;
        if (MODE == 0) {
            mn = -TAU_F * tsum;          // all dual state zero
        } else {
            float mC, mO = 0.0f;
            if (q < 8)       { mC=(float)mCv0[q];   if (MODE==2) mO=(float)mOv0[q]; }
            else if (q < 16) { mC=(float)mCv1[q-8]; if (MODE==2) mO=(float)mOv1[q-8]; }
            else             { mC=mCT;              if (MODE==2) mO=mOT; }
            tprev += (b < 8) ? (float)pp0[b] : (float)pp1[b-8];

            // sx_{k-1} = (mu_{k-1}-mu_{k-2})/tau + t_prev ; mx = sx - mubar
            float sxp = (mC - mO) * 36.0f + tprev;
            float mx  = sxp - (2.0f*mC - mO);
            float mo  = __shfl_xor(mx, 1);
            float snorm = sqrtf(mx*mx + mo*mo);
            if (snorm > 25.6f) mx *= 0.1f / snorm;   // nu*H ; nu/snorm
            mn = mC + TAU_F*(mx - tsum);
        }

        if (q < 8)       muo0[q]   = (half_t)mn;
        else if (q < 16) muo1[q-8] = (half_t)mn;
        else             muoT      = (half_t)mn;

        if (q <= 15-H) rsA += mn; else rsB += mn;
        C[b] += mn;
    }

    *reinterpret_cast<half8*>(&muO[vb])  = muo0;
    *reinterpret_cast<half8*>(&muO[vb1]) = muo1;
    muO[tail] = muoT;

    // partial musum recurrence (subset-valid), staged to part[H][z][lane]:
    // ms[z] = ms[z-1] + RS[z] - C[z-1], RS nonzero only at z=H, z=15-H
    float m = 0.0f;
    #pragma unroll
    for (int z = 0; z < LL; ++z) {
        if (z == H)    m += rsA;
        if (z == 15-H) m += rsB;
        if (z >= 1)    m -= C[z-1];
        part[H*1024 + z*64 + lane] = m;
    }
}

template<int MODE>
__global__ __launch_bounds__(512, 4) void k_smu_u(
    const float* __restrict__ f,
    const half_t* __restrict__ pxCur,   // px(it)   [d][n][z] fp16
    const half_t* __restrict__ pxOld,   // px(it-1) [d][n][z] fp16 (MODE>=1)
    const half_t* __restrict__ pt,
    const half_t* __restrict__ muC,     // mu_{k-1} (MODE>=1)
    half_t* __restrict__ muO,           // mu_{k-2} -> mu_k
    half_t* __restrict__ musum,         // [d][n][z] fp16 output
    float* __restrict__ u, half_t* __restrict__ ubar,
    float* __restrict__ nrj)
{
    __shared__ float part[8192];   // 32 KB: [h][z][lane], all slots written
    __shared__ float wsum[8];

    int tid  = threadIdx.x;
    int wv   = tid >> 6;          // wave id = row-set h (0..7)
    int lane = tid & 63;
    int pix  = lane >> 1;
    int d    = lane & 1;
    int n    = blockIdx.x*32 + pix;

    // -------- load p (current px) and pp (prev px), packed half8 --------
    const half8* pv = reinterpret_cast<const half8*>(pxCur + (size_t)d*NL + (size_t)n*LL);
    half8 ph0 = pv[0], ph1 = pv[1];
    half8 pp0, pp1;
    if (MODE >= 1) {
        const half8* ppv = reinterpret_cast<const half8*>(pxOld + (size_t)d*NL + (size_t)n*LL);
        pp0 = ppv[0]; pp1 = ppv[1];
    }

    // -------- phase A: s & mu (per wave = one row set) --------
    if      (wv == 0) do_set<0,MODE>(d,n,lane,ph0,ph1,pp0,pp1,muC,muO,part);
    else if (wv == 1) do_set<1,MODE>(d,n,lane,ph0,ph1,pp0,pp1,muC,muO,part);
    else if (wv == 2) do_set<2,MODE>(d,n,lane,ph0,ph1,pp0,pp1,muC,muO,part);
    else if (wv == 3) do_set<3,MODE>(d,n,lane,ph0,ph1,pp0,pp1,muC,muO,part);
    else if (wv == 4) do_set<4,MODE>(d,n,lane,ph0,ph1,pp0,pp1,muC,muO,part);
    else if (wv == 5) do_set<5,MODE>(d,n,lane,ph0,ph1,pp0,pp1,muC,muO,part);
    else if (wv == 6) do_set<6,MODE>(d,n,lane,ph0,ph1,pp0,pp1,muC,muO,part);
    else              do_set<7,MODE>(d,n,lane,ph0,ph1,pp0,pp1,muC,muO,part);

    __syncthreads();   // all staged partials visible

    // -------- reduce partials over h, store fp16 musum --------
    // round r: z2 = (tid>>6)+8r, inner = tid&63 -> consecutive LDS addrs
    #pragma unroll
    for (int r = 0; r < 2; ++r) {
        int z2    = (tid >> 6) + r*8;
        int inner = tid & 63;
        float s = 0.0f;
        #pragma unroll
        for (int hh = 0; hh < 8; ++hh) s += part[hh*1024 + z2*64 + inner];
        int d2 = inner & 1, pix2 = inner >> 1;
        musum[(size_t)d2*NL + ((size_t)blockIdx.x*32 + pix2)*LL + z2] = (half_t)s;
    }

    // -------- phase B: primal u update (1 z per thread) --------
    // independent of phase A (depends only on prox outputs)
    {
        int t  = blockIdx.x*512 + tid;   // [0, NL)
        int z  = t & (LL-1);
        int n2 = t >> 4;
        int i2 = n2 >> 8;
        int j2 = n2 & (WW-1);

        float p0c = (float)pxCur[t];
        float p1c = (float)pxCur[NL + t];
        float d0 = ((i2 < HH-1) ? p0c : 0.0f) - ((i2 > 0) ? (float)pxCur[t - WW*LL] : 0.0f);
        float d1 = ((j2 < WW-1) ? p1c : 0.0f) - ((j2 > 0) ? (float)pxCur[NL + t - LL] : 0.0f);
        float ptc = (float)pt[t];
        float dt = ((z < LL-1) ? ptc : 0.0f) - ((z > 0) ? (float)pt[t - 1] : 0.0f);

        float uo = (MODE == 0) ? f[n2] : u[t];
        float Dv = uo + TAUU_F * ((d0 + d1) * 256.0f + dt * 16.0f);
        float un = clampf(Dv, 0.0f, 1.0f);
        if (z == 0)     un = 1.0f;
        if (z == LL-1)  un = 0.0f;
        u[t]    = un;
        ubar[t] = (half_t)(2.0f*un - uo);

        if (MODE == 0) {   // nrj only at it=0 (it%10==0 with repeats=10)
            float v = fabsf(un - uo);
            #pragma unroll
            for (int off = 32; off > 0; off >>= 1) v += __shfl_down(v, off);
            if ((tid & 63) == 0) wsum[wv] = v;
            __syncthreads();
            if (tid == 0) {
                float s = 0.0f;
                #pragma unroll
                for (int q = 0; q < 8; ++q) s += wsum[q];
                atomicAdd(nrj, s);
            }
        }
    }
}

// ---------------- tail scalars ----------------------------------------------
__global__ void k_final(const float* __restrict__ nrj, float* __restrict__ out_tail)
{
    if (threadIdx.x == 0) {
        float e = *nrj;
        out_tail[0] = e;
        out_tail[1] = e * (1.0f/1048576.0f);   // nrj / (H*W*1*l)
        out_tail[2] = 0.0f;
    }
}

extern "C" void kernel_launch(void* const* d_in, const int* in_sizes, int n_in,
                              void* d_out, int out_size, void* d_ws, size_t ws_size,
                              hipStream_t stream)
{
    const float* f = (const float*)d_in[0];
    float* out = (float*)d_out;

    char* w = (char*)d_ws;
    size_t off = 0;
    auto allocf = [&](size_t nfloats) {
        float* p = (float*)(w + off);
        off += nfloats * sizeof(float);
        return p;
    };
    auto alloch = [&](size_t nhalf) {
        half_t* p = (half_t*)(w + off);
        off += nhalf * sizeof(half_t);
        return p;
    };
    half_t* muA    = alloch((size_t)NPIX * PP2);   // 35.7 MB
    half_t* muB    = alloch((size_t)NPIX * PP2);   // 35.7 MB
    half_t* musum  = alloch(2*(size_t)NL);         // 4.2 MB
    half_t* pxA    = alloch(2*(size_t)NL);         // 4.2 MB
    half_t* pxB    = alloch(2*(size_t)NL);         // 4.2 MB
    half_t* pt     = alloch((size_t)NL);           // 2.1 MB
    half_t* ubar   = alloch((size_t)NL);           // 2.1 MB
    float*  u      = allocf((size_t)NL);           // 4.2 MB
    float*  nrj    = allocf(64);
    (void)ws_size; (void)in_sizes; (void)n_in; (void)out_size;

    // NO memset / init kernel: it=0 is fully specialized (state analytically
    // zero, never read); it=1 skips the muO read (poisoned buffer is fully
    // overwritten at it=0/1). Every buffer's first access per call is a write.
    half_t* pxC = pxA;  // px(it)
    half_t* pxO = pxB;  // px(it-1)
    half_t* mC  = muA;  // mu_{k-1}
    half_t* mO  = muB;  // mu_{k-2} -> becomes mu_k
    for (int it = 0; it < 10; ++it) {
        if (it == 0) {
            k_prox<0><<<NL/256, 256, 0, stream>>>(f, ubar, pxO, pxC, pt, musum, nrj);
            k_smu_u<0><<<NPIX/32, 512, 0, stream>>>(f, pxC, pxO, pt, mC, mO, musum, u, ubar, nrj);
        } else if (it == 1) {
            k_prox<1><<<NL/256, 256, 0, stream>>>(f, ubar, pxO, pxC, pt, musum, nrj);
            k_smu_u<1><<<NPIX/32, 512, 0, stream>>>(f, pxC, pxO, pt, mC, mO, musum, u, ubar, nrj);
        } else {
            k_prox<1><<<NL/256, 256, 0, stream>>>(f, ubar, pxO, pxC, pt, musum, nrj);
            k_smu_u<2><<<NPIX/32, 512, 0, stream>>>(f, pxC, pxO, pt, mC, mO, musum, u, ubar, nrj);
        }
        { half_t* tmp = pxC; pxC = pxO; pxO = tmp; }
        { half_t* tmp = mC;  mC  = mO;  mO  = tmp; }  // mO-buffer holds mu_k
    }

    hipMemcpyAsync(out, u, (size_t)NL*sizeof(float), hipMemcpyDeviceToDevice, stream);
    k_final<<<1, 64, 0, stream>>>(nrj, out + NL);
}